// Round 1
// baseline (657.114 us; speedup 1.0000x reference)
//
#include <hip/hip_runtime.h>

// Correlation layer: out[b, dh*9+dw, h, w] =
//   (1/196) * sum_c in1[b,c,h,w] * in2[b,c, refl(h+dh-4), refl(w+dw-4)]
// Shapes: in1,in2 = [8,196,128,224] f32 ; out = [8,81,128,224] f32
//
// Block = one (b,h): 512 threads = 9 dh-groups (dh-major) x 56 slots x 4 px.
// Per channel pair: stage 9 reflected in2 rows into LDS (vector float4 for
// interior, 8 scalar edge elems/row), reg-buffered prefetch of next pair.
// Compute: 3x ds_read_b128 window + global float4 in1 (L1), 36 FMA/ch/thread.

constexpr int NB = 8, NC = 196, NH = 128, NW = 224;
constexpr int ND = 9;            // displacements per axis
constexpr int PADV = 4;
constexpr int WS = 232;          // staged row width (floats): s = (w+dw) in [0,232)
constexpr int KC = 2;            // channels per round
constexpr int NSLOT = 56;        // w-groups of 4
constexpr int ACTIVE = ND * NSLOT;   // 504 compute threads
constexpr int TPB = 512;
constexpr int HWSZ = NH * NW;    // 28672

__device__ __forceinline__ int refl(int v, int n) {
    v = v < 0 ? -v : v;
    return v >= n ? 2 * n - 2 - v : v;
}

__global__ __launch_bounds__(TPB)
void corr_kernel(const float* __restrict__ in1,
                 const float* __restrict__ in2,
                 float* __restrict__ out)
{
    __shared__ float s_win[KC][ND][WS];   // 16704 B

    const int tid = threadIdx.x;
    const int bh  = blockIdx.x;
    const int b   = bh / NH;
    const int h   = bh - b * NH;

    // ---- staging precompute (fixed across channel rounds) ----
    // Part A: interior vector slots: KC*ND*56 = 1008 float4 slots, s = 4+4g, x = 4g
    const float* gA[2];
    int  lA[2];
    bool vA[2];
#pragma unroll
    for (int k = 0; k < 2; ++k) {
        int v  = tid + k * TPB;
        vA[k]  = v < KC * ND * NSLOT;
        int vv = vA[k] ? v : 0;
        int cc = vv / (ND * NSLOT);
        int r  = vv - cc * (ND * NSLOT);
        int dh = r / NSLOT;
        int g  = r - dh * NSLOT;
        int y  = refl(h + dh - PADV, NH);
        gA[k]  = in2 + ((b * NC + cc) * NH + y) * NW + 4 * g;
        lA[k]  = (cc * ND + dh) * WS + 4 + 4 * g;
    }
    // Part B: edge scalar slots: KC*ND*8 = 144
    //   e<4: s=e,     x=4-e   (left reflect)
    //   e>=4: s=224+e, x=226-e (right reflect)
    const float* gB = in2;
    int  lB = 0;
    const bool vB = tid < KC * ND * 8;
    {
        int v  = vB ? tid : 0;
        int cc = v / (ND * 8);
        int r  = v - cc * (ND * 8);
        int dh = r / 8;
        int e  = r - dh * 8;
        int s  = e < 4 ? e : 224 + e;
        int x  = e < 4 ? 4 - e : 226 - e;
        int y  = refl(h + dh - PADV, NH);
        gB = in2 + ((b * NC + cc) * NH + y) * NW + x;
        lB = (cc * ND + dh) * WS + s;
    }

    // ---- compute-thread identity (dh-major for coalescing/conflict-free LDS) ----
    const int  cdh  = tid / NSLOT;          // 0..8
    const int  slot = tid - cdh * NSLOT;    // 0..55
    const int  w0   = slot * 4;
    const bool compute = tid < ACTIVE;
    const float* a1p = in1 + ((b * NC) * NH + h) * NW + w0;   // + c*HWSZ per channel

    float acc[ND][4];
#pragma unroll
    for (int d = 0; d < ND; ++d)
#pragma unroll
        for (int p = 0; p < 4; ++p) acc[d][p] = 0.f;

    // ---- register-buffered prefetch of round 0 ----
    float4 bufA[2];
    float  bufB = 0.f;
#pragma unroll
    for (int k = 0; k < 2; ++k)
        if (vA[k]) bufA[k] = *(const float4*)(gA[k]);
    if (vB) bufB = gB[0];

    for (int c0 = 0; c0 < NC; c0 += KC) {
        __syncthreads();                    // LDS free from previous round
#pragma unroll
        for (int k = 0; k < 2; ++k)
            if (vA[k]) *(float4*)&((float*)s_win)[lA[k]] = bufA[k];
        if (vB) ((float*)s_win)[lB] = bufB;
        __syncthreads();

        // issue next round's global loads (latency hidden behind compute)
        const int c1 = c0 + KC;
        if (c1 < NC) {
            const int off = c1 * HWSZ;
#pragma unroll
            for (int k = 0; k < 2; ++k)
                if (vA[k]) bufA[k] = *(const float4*)(gA[k] + off);
            if (vB) bufB = gB[off];
        }

        if (compute) {
#pragma unroll
            for (int cc = 0; cc < KC; ++cc) {
                const float* wrow = &s_win[cc][cdh][w0];
                float4 wv0 = *(const float4*)(wrow);
                float4 wv1 = *(const float4*)(wrow + 4);
                float4 wv2 = *(const float4*)(wrow + 8);
                const float wn[12] = {wv0.x, wv0.y, wv0.z, wv0.w,
                                      wv1.x, wv1.y, wv1.z, wv1.w,
                                      wv2.x, wv2.y, wv2.z, wv2.w};
                float4 a = *(const float4*)(a1p + (c0 + cc) * HWSZ);
#pragma unroll
                for (int d = 0; d < ND; ++d) {
                    acc[d][0] += a.x * wn[d + 0];
                    acc[d][1] += a.y * wn[d + 1];
                    acc[d][2] += a.z * wn[d + 2];
                    acc[d][3] += a.w * wn[d + 3];
                }
            }
        }
    }

    if (compute) {
        const float scale = 1.0f / 196.0f;
#pragma unroll
        for (int d = 0; d < ND; ++d) {
            float4 o;
            o.x = acc[d][0] * scale;
            o.y = acc[d][1] * scale;
            o.z = acc[d][2] * scale;
            o.w = acc[d][3] * scale;
            float* op = out + (((b * (ND * ND)) + cdh * ND + d) * NH + h) * NW + w0;
            *(float4*)op = o;
        }
    }
}

extern "C" void kernel_launch(void* const* d_in, const int* in_sizes, int n_in,
                              void* d_out, int out_size, void* d_ws, size_t ws_size,
                              hipStream_t stream)
{
    const float* in1 = (const float*)d_in[0];
    const float* in2 = (const float*)d_in[1];
    float* outp = (float*)d_out;
    dim3 grid(NB * NH);
    dim3 block(TPB);
    hipLaunchKernelGGL(corr_kernel, grid, block, 0, stream, in1, in2, outp);
}